// Round 8
// baseline (24.798 us; speedup 1.0000x reference)
//
#include <hip/hip_runtime.h>
#include <hip/hip_bf16.h>

#define BB 8
#define NN 256
#define DD 64
#define HH 8
#define PP 4

typedef __attribute__((ext_vector_type(8))) short bf16x8;
typedef __attribute__((ext_vector_type(4))) float f32x4;
typedef __attribute__((ext_vector_type(4))) int i32x4;

// HW bf16 convert (RNE): compiler fuses float->__bf16 pairs into v_cvt_pk_bf16_f32
static __device__ __forceinline__ unsigned pack2(float lo, float hi) {
  __bf16 a = (__bf16)lo, b = (__bf16)hi;
  unsigned short ua = __builtin_bit_cast(unsigned short, a);
  unsigned short ub = __builtin_bit_cast(unsigned short, b);
  return (unsigned)ua | ((unsigned)ub << 16);
}

static __device__ __forceinline__ bf16x8 pack8(float4 a, float4 b) {
  union { bf16x8 v; unsigned u[4]; } r;
  r.u[0] = pack2(a.x, a.y); r.u[1] = pack2(a.z, a.w);
  r.u[2] = pack2(b.x, b.y); r.u[3] = pack2(b.z, b.w);
  return r.v;
}

// LDS fragment address: fidx in [0,24), lane-slot in [0,64), 16B units.
// XOR swizzle spreads the write side; read side is a permutation within each
// 128B row (contiguous-1KB wave read stays conflict-free). Identical to the
// R5-proven function.
static __device__ __forceinline__ int frag_addr(int fidx, int lane) {
  return ((fidx * 64 + lane) * 16) ^ ((((lane >> 3) ^ fidx) & 7) << 4);
}

// Fused: Z = conv-row-factor in LDS (bf16 MFMA B-frag layout), then
// out[b,h,i,j] = (sum_ki sum_d x[b,i+ki-1,d]*Z[h,ki,j,d] + conv_b[h]) * (edge[b,i,j,:].edge_w[h,:])
// Tile: 64i x 16j x 4 heads (head-half per block). 256 thr = 4 waves (= rowq).
// Grid = 2hh * 8b * 4it * 16jt = 1024 -> 4 blocks/CU, 4 waves/SIMD, 24KB LDS.
// hh at 512-stride keeps hh-pairs on the same XCD (edge L2-shared).
__global__ __launch_bounds__(256, 4)
void fused_kernel(const float* __restrict__ x, const float* __restrict__ edge,
                  const float* __restrict__ conv_w, const float* __restrict__ conv_b,
                  const float* __restrict__ edge_w, float* __restrict__ out) {
  __shared__ bf16x8 frag_s[24 * 64];     // 24576 B
  char* fragb = (char*)frag_s;

  const int lid = blockIdx.x;
  const int hh  = lid >> 9;              // head half 0/1
  const int rest = lid & 511;
  const int jt = rest & 15;
  const int it = (rest >> 4) & 3;
  const int b  = rest >> 6;
  const int h0 = hh * 4;
  const int j0 = jt * 16;

  const int tid  = threadIdx.x;
  const int lane = tid & 63;
  const int wave = tid >> 6;             // 0..3 = rowq; also = local head for Z
  const int iw   = it * 64 + wave * 16;
  const int lrow = lane & 15;            // i within 16-group / j col of B frag
  const int lkk  = lane >> 4;            // k-octet / D^T row-quad (j)

  // ---- A fragments: x rows iw-1..iw+16 (SAME padding), fp32->bf16 ----
  bf16x8 a[3][2];
#pragma unroll
  for (int ki = 0; ki < 3; ++ki) {
    int r = iw + lrow + ki - 1;
    bool ok = (r >= 0) && (r < NN);
#pragma unroll
    for (int dh = 0; dh < 2; ++dh) {
      bf16x8 v = {0, 0, 0, 0, 0, 0, 0, 0};
      if (ok) {
        const float* px = x + ((size_t)(b * NN + r)) * DD + dh * 32 + lkk * 8;
        float4 f0 = *(const float4*)(px);
        float4 f1 = *(const float4*)(px + 4);
        v = pack8(f0, f1);
      }
      a[ki][dh] = v;
    }
  }

  // ---- edge prefetch: lane owns (i = iw+lrow, j = j0+lkk*4 .. +3); issued before
  // the Z phase so HBM latency hides under ~800cy of Z-FMA + barrier ----
  float4 e4[4];
  {
    const float* pe = edge + ((size_t)(b * NN + (iw + lrow)) * NN + (j0 + lkk * 4)) * PP;
#pragma unroll
    for (int r = 0; r < 4; ++r) e4[r] = *(const float4*)(pe + r * PP);
  }

  // ---- Z phase: wave w computes head (h0+w)'s frags.
  // Per-32-thread mapping is EXACTLY R5's (zo = d-octet, zjq = j-quartet);
  // lane bit 5 splits the jj range {0,1} vs {2,3}. 6 frag-units/thread.
  {
    const int t5  = lane & 31;
    const int zo  = t5 >> 2;             // d-octet 0..7
    const int zjq = t5 & 3;              // j-quartet 0..3
    const int jjb = (lane >> 5) * 2;     // jj base 0 or 2
    const int zd0 = zo * 8;
    const int jq0 = j0 + zjq * 4 + jjb;  // first output j of this thread

    float xv[4][8];                      // x rows jq0-1 .. jq0+2
#pragma unroll
    for (int m = 0; m < 4; ++m) {
      int jg = jq0 - 1 + m;
      if (jg >= 0 && jg < NN) {
        const float* px = x + ((size_t)(b * NN + jg)) * DD + zd0;
        float4 f0 = *(const float4*)(px);
        float4 f1 = *(const float4*)(px + 4);
        xv[m][0] = f0.x; xv[m][1] = f0.y; xv[m][2] = f0.z; xv[m][3] = f0.w;
        xv[m][4] = f1.x; xv[m][5] = f1.y; xv[m][6] = f1.z; xv[m][7] = f1.w;
      } else {
#pragma unroll
        for (int e = 0; e < 8; ++e) xv[m][e] = 0.f;
      }
    }

    i32x4 vv[3][2];
#pragma unroll
    for (int ep = 0; ep < 4; ++ep) {
      float w2[18];   // conv_w rows for e = 2*ep, 2*ep+1 (9 floats each, contiguous)
      __builtin_memcpy(w2, conv_w + (size_t)((h0 + wave) * DD + zd0 + 2 * ep) * 9,
                       18 * sizeof(float));
#pragma unroll
      for (int ki = 0; ki < 3; ++ki) {
#pragma unroll
        for (int jj = 0; jj < 2; ++jj) {
          float s0 = w2[ki * 3 + 0] * xv[jj + 0][2 * ep] +
                     w2[ki * 3 + 1] * xv[jj + 1][2 * ep] +
                     w2[ki * 3 + 2] * xv[jj + 2][2 * ep];
          float s1 = w2[9 + ki * 3 + 0] * xv[jj + 0][2 * ep + 1] +
                     w2[9 + ki * 3 + 1] * xv[jj + 1][2 * ep + 1] +
                     w2[9 + ki * 3 + 2] * xv[jj + 2][2 * ep + 1];
          vv[ki][jj][ep] = (int)pack2(s0, s1);
        }
      }
    }

#pragma unroll
    for (int ki = 0; ki < 3; ++ki) {
      int fidx = (wave * 3 + ki) * 2 + (zo >> 2);
#pragma unroll
      for (int jj = 0; jj < 2; ++jj) {
        int lw = (zo & 3) * 16 + zjq * 4 + jjb + jj;
        *(i32x4*)(fragb + frag_addr(fidx, lw)) = vv[ki][jj];
      }
    }
  }

  __syncthreads();

  // ---- MFMA: 4 heads x 3 ki x 2 dh = 24 per wave, operands swapped -> D^T ----
  f32x4 acc[4];
#pragma unroll
  for (int h = 0; h < 4; ++h) acc[h] = (f32x4){0.f, 0.f, 0.f, 0.f};

#pragma unroll
  for (int h = 0; h < 4; ++h) {
#pragma unroll
    for (int ki = 0; ki < 3; ++ki) {
#pragma unroll
      for (int dh = 0; dh < 2; ++dh) {
        int fidx = (h * 3 + ki) * 2 + dh;
        bf16x8 bz = *(const bf16x8*)(fragb + frag_addr(fidx, lane));
        acc[h] = __builtin_amdgcn_mfma_f32_16x16x32_bf16(bz, a[ki][dh], acc[h], 0, 0, 0);
      }
    }
  }

  // ---- epilogue: edge projection + scale + vectorized store.
  // edge_w/conv_b loads are uniform -> scalar loads, no VGPR cost. ----
  const int i = iw + lrow;
#pragma unroll
  for (int h = 0; h < 4; ++h) {
    float wx = edge_w[(h0 + h) * PP + 0];
    float wy = edge_w[(h0 + h) * PP + 1];
    float wz = edge_w[(h0 + h) * PP + 2];
    float ww = edge_w[(h0 + h) * PP + 3];
    float cb = conv_b[h0 + h];
    f32x4 o;
#pragma unroll
    for (int r = 0; r < 4; ++r) {
      float eh = e4[r].x * wx + e4[r].y * wy + e4[r].z * wz + e4[r].w * ww;
      o[r] = (acc[h][r] + cb) * eh;
    }
    *(f32x4*)(out + ((size_t)(b * HH + h0 + h) * NN + i) * NN + j0 + lkk * 4) = o;
  }
}

extern "C" void kernel_launch(void* const* d_in, const int* in_sizes, int n_in,
                              void* d_out, int out_size, void* d_ws, size_t ws_size,
                              hipStream_t stream) {
  const float* x      = (const float*)d_in[0];
  const float* edge   = (const float*)d_in[1];
  const float* conv_w = (const float*)d_in[2];
  const float* conv_b = (const float*)d_in[3];
  const float* edge_w = (const float*)d_in[4];
  float* out = (float*)d_out;

  fused_kernel<<<2 * BB * 4 * 16, 256, 0, stream>>>(x, edge, conv_w, conv_b, edge_w, out);
}

// Round 9
// 17.932 us; speedup vs baseline: 1.3829x; 1.3829x over previous
//
#include <hip/hip_runtime.h>
#include <hip/hip_bf16.h>

#define BB 8
#define NN 256
#define DD 64
#define HH 8
#define PP 4

typedef __attribute__((ext_vector_type(8))) short bf16x8;
typedef __attribute__((ext_vector_type(4))) float f32x4;

static __device__ __forceinline__ unsigned short bfbits(float f) {
  union { float f; unsigned u; } v; v.f = f;
  unsigned u = v.u;
  u += 0x7FFFu + ((u >> 16) & 1u);   // round-to-nearest-even
  return (unsigned short)(u >> 16);
}

static __device__ __forceinline__ bf16x8 pack8(float4 a, float4 b) {
  bf16x8 v;
  v[0] = (short)bfbits(a.x); v[1] = (short)bfbits(a.y);
  v[2] = (short)bfbits(a.z); v[3] = (short)bfbits(a.w);
  v[4] = (short)bfbits(b.x); v[5] = (short)bfbits(b.y);
  v[6] = (short)bfbits(b.z); v[7] = (short)bfbits(b.w);
  return v;
}

// LDS fragment address: fidx in [0,48), lane in [0,64), 16B units.
// XOR swizzle breaks write-phase bank conflicts; read side stays a
// permutation within each 128B block (contiguous-1KB wave read = conflict-free).
static __device__ __forceinline__ int frag_addr(int fidx, int lane) {
  return ((fidx * 64 + lane) * 16) ^ ((((lane >> 3) ^ fidx) & 7) << 4);
}

// Fused: Z = conv-row-factor in LDS (bf16 MFMA-fragment layout), then
// out[b,h,i,j] = (sum_ki sum_d x[b,i+ki-1,d]*Z[h,ki,j,d] + conv_b[h]) * (edge[b,i,j,:]. edge_w[h,:])
// Tile: 64 rows x 16 cols x all 8 heads per block. Grid = 8b*4it*16jt = 512.
__global__ __launch_bounds__(256, 3)
void fused_kernel(const float* __restrict__ x, const float* __restrict__ edge,
                  const float* __restrict__ conv_w, const float* __restrict__ conv_b,
                  const float* __restrict__ edge_w, float* __restrict__ out) {
  __shared__ bf16x8 frag_s[48 * 64];     // 49152 B
  char* fragb = (char*)frag_s;

  const int bid = blockIdx.x;
  const int jt = bid & 15;
  const int it = (bid >> 4) & 3;
  const int b  = bid >> 6;
  const int j0 = jt * 16;
  const int tid  = threadIdx.x;
  const int lane = tid & 63;
  const int wave = tid >> 6;
  const int lrow = lane & 15;            // A-frag row / B col / C col
  const int lkk  = lane >> 4;            // k-octet / C row-quad
  const int i0   = it * 64 + wave * 16;  // this wave's 16 output rows

  // ---- A fragments: rows i0..i0+15 with +-1 halo (SAME padding), fp32->bf16 ----
  bf16x8 a[3][2];
#pragma unroll
  for (int ki = 0; ki < 3; ++ki) {
    int r = i0 + lrow + ki - 1;
    bool ok = (r >= 0) && (r < NN);
#pragma unroll
    for (int dh = 0; dh < 2; ++dh) {
      bf16x8 v = {0, 0, 0, 0, 0, 0, 0, 0};
      if (ok) {
        const float* px = x + ((size_t)(b * NN + r)) * DD + dh * 32 + lkk * 8;
        float4 f0 = *(const float4*)(px);
        float4 f1 = *(const float4*)(px + 4);
        v = pack8(f0, f1);
      }
      a[ki][dh] = v;
    }
  }

  // ---- Z compute into LDS, fragment layout ----
  // thread -> (head zh, d-octet zo, j-quartet zjq); 12 fragment units each
  {
    const int zh  = tid >> 5;
    const int zo  = (tid >> 2) & 7;
    const int zjq = tid & 3;
    const int zd0 = zo * 8;

    float xv[6][8];
#pragma unroll
    for (int m = 0; m < 6; ++m) {
      int jg = j0 + zjq * 4 - 1 + m;
      if (jg >= 0 && jg < NN) {
        const float* px = x + ((size_t)(b * NN + jg)) * DD + zd0;
        float4 f0 = *(const float4*)(px);
        float4 f1 = *(const float4*)(px + 4);
        xv[m][0] = f0.x; xv[m][1] = f0.y; xv[m][2] = f0.z; xv[m][3] = f0.w;
        xv[m][4] = f1.x; xv[m][5] = f1.y; xv[m][6] = f1.z; xv[m][7] = f1.w;
      } else {
#pragma unroll
        for (int e = 0; e < 8; ++e) xv[m][e] = 0.f;
      }
    }

#pragma unroll
    for (int ki = 0; ki < 3; ++ki) {
      float wv[8][3];
#pragma unroll
      for (int e = 0; e < 8; ++e) {
        const float* pw = conv_w + (size_t)(zh * DD + zd0 + e) * 9 + ki * 3;
        wv[e][0] = pw[0]; wv[e][1] = pw[1]; wv[e][2] = pw[2];
      }
      int fidx = (zh * 3 + ki) * 2 + (zo >> 2);
#pragma unroll
      for (int jj = 0; jj < 4; ++jj) {
        bf16x8 v;
#pragma unroll
        for (int e = 0; e < 8; ++e) {
          float s = wv[e][0] * xv[jj][e] + wv[e][1] * xv[jj + 1][e] +
                    wv[e][2] * xv[jj + 2][e];
          v[e] = (short)bfbits(s);
        }
        int lw = (zo & 3) * 16 + zjq * 4 + jj;
        *(bf16x8*)(fragb + frag_addr(fidx, lw)) = v;
      }
    }
  }
  __syncthreads();

  // ---- edge prefetch (this wave's 16 rows x 16 cols, read exactly once/block) ----
  float4 e4[4];
#pragma unroll
  for (int r = 0; r < 4; ++r) {
    int i = i0 + lkk * 4 + r;
    e4[r] = *(const float4*)(edge + ((size_t)(b * NN + i) * NN + (j0 + lrow)) * PP);
  }

  // ---- MFMA: 8 heads x 3 ki x 2 dh = 48 per wave ----
  f32x4 acc[HH];
#pragma unroll
  for (int h = 0; h < HH; ++h) acc[h] = (f32x4){0.f, 0.f, 0.f, 0.f};

#pragma unroll
  for (int h = 0; h < HH; ++h) {
#pragma unroll
    for (int ki = 0; ki < 3; ++ki) {
#pragma unroll
      for (int dh = 0; dh < 2; ++dh) {
        int fidx = (h * 3 + ki) * 2 + dh;
        bf16x8 bz = *(const bf16x8*)(fragb + frag_addr(fidx, lane));
        acc[h] = __builtin_amdgcn_mfma_f32_16x16x32_bf16(a[ki][dh], bz, acc[h], 0, 0, 0);
      }
    }
  }

  // ---- epilogue: edge projection + scale + store ----
  float4 ew[HH];
  float  cb[HH];
#pragma unroll
  for (int h = 0; h < HH; ++h) {
    ew[h] = *(const float4*)(edge_w + h * PP);
    cb[h] = conv_b[h];
  }

#pragma unroll
  for (int r = 0; r < 4; ++r) {
    int i = i0 + lkk * 4 + r;
    int j = j0 + lrow;
#pragma unroll
    for (int h = 0; h < HH; ++h) {
      float eh = e4[r].x * ew[h].x + e4[r].y * ew[h].y +
                 e4[r].z * ew[h].z + e4[r].w * ew[h].w;
      out[((size_t)(b * HH + h) * NN + i) * NN + j] = (acc[h][r] + cb[h]) * eh;
    }
  }
}

extern "C" void kernel_launch(void* const* d_in, const int* in_sizes, int n_in,
                              void* d_out, int out_size, void* d_ws, size_t ws_size,
                              hipStream_t stream) {
  const float* x      = (const float*)d_in[0];
  const float* edge   = (const float*)d_in[1];
  const float* conv_w = (const float*)d_in[2];
  const float* conv_b = (const float*)d_in[3];
  const float* edge_w = (const float*)d_in[4];
  float* out = (float*)d_out;

  fused_kernel<<<BB * 4 * 16, 256, 0, stream>>>(x, edge, conv_w, conv_b, edge_w, out);
}